// Round 9
// baseline (2747.778 us; speedup 1.0000x reference)
//
#include <hip/hip_runtime.h>
#include <math.h>

// ---------------------------------------------------------------------------
// TypeGraphModel: conv encoder (bf16 MFMA) + persistent mega-kernel for the
// transformer + heads (hand-rolled grid barrier, 512 co-resident blocks).
// N=1024, D=1024, CC=64, TP=16, EMB=128, NH=4, HD=32, L=2, FF=2048
// ---------------------------------------------------------------------------

typedef float f32x4 __attribute__((ext_vector_type(4)));
typedef short bf16x8 __attribute__((ext_vector_type(8)));
typedef unsigned short u16;
typedef unsigned short us4 __attribute__((ext_vector_type(4)));
typedef unsigned int u32;

__device__ __forceinline__ float gelu_fast(float v) {
  float ax = fabsf(v) * 0.70710678118654752440f;
  float t = __builtin_amdgcn_rcpf(fmaf(0.3275911f, ax, 1.f));
  float p = fmaf(1.061405429f, t, -1.453152027f);
  p = fmaf(p, t, 1.421413741f);
  p = fmaf(p, t, -0.284496736f);
  p = fmaf(p, t, 0.254829592f);
  p = p * t;
  float e = __expf(-ax * ax);
  float erfa = fmaf(-p, e, 1.f);
  float erfv = copysignf(erfa, v);
  return 0.5f * v * (1.f + erfv);
}

__device__ __forceinline__ u16 to_bf16(float v) {
  u32 u = __float_as_uint(v);
  return (u16)((u + 0x7FFFu + ((u >> 16) & 1u)) >> 16);
}
__device__ __forceinline__ u32 packbf(float a, float b) {
  return (u32)to_bf16(a) | ((u32)to_bf16(b) << 16);
}

// ---------------- fused conv1+bn+gelu -> conv2(MFMA)+bn+gelu+pool -----------
__global__ __launch_bounds__(256) void encoder_kernel(
    const float* __restrict__ x,
    const float* __restrict__ w1, const float* __restrict__ b1,
    const float* __restrict__ g1, const float* __restrict__ be1,
    const float* __restrict__ m1, const float* __restrict__ v1,
    const float* __restrict__ w2, const float* __restrict__ b2,
    const float* __restrict__ g2, const float* __restrict__ be2,
    const float* __restrict__ m2, const float* __restrict__ v2,
    u16* __restrict__ pooled_bf)
{
  const int blk = blockIdx.x;
  const int n = blk >> 1, hb = blk & 1;
  const int P0 = hb * 512;
  const int tid = threadIdx.x;

  __shared__ __align__(16) float xs[524];
  __shared__ __align__(16) u16 h1s[516 * 40];

  for (int s = tid; s < 522; s += 256) {
    int gp = P0 - 5 + s;
    xs[s] = (gp >= 0 && gp < 1024) ? x[n * 1024 + gp] : 0.f;
  }

  const int l = tid & 63;
  const int w = tid >> 6;
  const int col = l & 15;
  const int kh = l >> 4;
  const int oc = w * 16 + col;
  bf16x8 bf[5];
#pragma unroll
  for (int t = 0; t < 5; t++) {
#pragma unroll
    for (int e = 0; e < 8; e++)
      bf[t][e] = (short)to_bf16(w2[(oc * 32 + kh * 8 + e) * 5 + t]);
  }
  const float sc2 = g2[oc] * rsqrtf(v2[oc] + 1e-5f);
  const float sh2 = (b2[oc] - m2[oc]) * sc2 + be2[oc];

  const int ch = tid & 31;
  float wk[7];
#pragma unroll
  for (int k = 0; k < 7; k++) wk[k] = w1[ch * 7 + k];
  const float s1 = g1[ch] * rsqrtf(v1[ch] + 1e-5f);
  const float t1 = (b1[ch] - m1[ch]) * s1 + be1[ch];

  __syncthreads();

  const int rb = tid >> 5;
  for (int r = rb; r < 516; r += 8) {
    float acc = 0.f;
#pragma unroll
    for (int k = 0; k < 7; k++) acc += wk[k] * xs[r + k];
    int pos = P0 - 2 + r;
    u16 hv = to_bf16(gelu_fast(fmaf(acc, s1, t1)));
    h1s[r * 40 + ch] = (pos >= 0 && pos < 1024) ? hv : (u16)0;
  }
  __syncthreads();

  float pool = 0.f;
#pragma unroll 4
  for (int pt = 0; pt < 32; pt++) {
    f32x4 acc = {0.f, 0.f, 0.f, 0.f};
    const u16* ap = &h1s[(pt * 16 + col) * 40 + kh * 8];
#pragma unroll
    for (int t = 0; t < 5; t++) {
      bf16x8 af = *(const bf16x8*)(ap + t * 40);
      acc = __builtin_amdgcn_mfma_f32_16x16x32_bf16(af, bf[t], acc, 0, 0, 0);
    }
    float s = 0.f;
#pragma unroll
    for (int rr = 0; rr < 4; rr++) s += gelu_fast(fmaf(acc[rr], sc2, sh2));
    pool += s;
    if ((pt & 3) == 3) {
      pool += __shfl_xor(pool, 16);
      pool += __shfl_xor(pool, 32);
      if (l < 16)
        pooled_bf[(n * 64 + oc) * 16 + hb * 8 + (pt >> 2)] =
            to_bf16(pool * (1.f / 64.f));
      pool = 0.f;
    }
  }
}

// ---------------- device-scope grid barrier (512 co-resident blocks) --------
__device__ __forceinline__ void gsync(unsigned* bar, int bi) {
  __syncthreads();
  if (threadIdx.x == 0) {
    __threadfence();                       // release prior global writes
    atomicAdd(&bar[bi], 1u);
    while (__hip_atomic_load(&bar[bi], __ATOMIC_ACQUIRE,
                             __HIP_MEMORY_SCOPE_AGENT) < 512u)
      __builtin_amdgcn_s_sleep(1);
  }
  __syncthreads();
  __threadfence();                         // acquire for all threads
}

// ---------------- per-wave GEMM tile task ----------------------------------
template<int NR, int K, bool RELU, bool VT>
__device__ __forceinline__ void mm_task(
    int m0, int n0, const u16* A, int lda, const u16* B, int ldb,
    const float* bias, float* Cf, u16* Cb, u16* vt, int ldc, int lane)
{
  const int r = lane & 15, kh = lane >> 4;
  f32x4 acc[2][NR];
#pragma unroll
  for (int i = 0; i < 2; i++)
#pragma unroll
    for (int j = 0; j < NR; j++) acc[i][j] = (f32x4){0.f, 0.f, 0.f, 0.f};

  const u16* Ap0 = A + (size_t)(m0 + r) * lda + kh * 8;
  const u16* Ap1 = Ap0 + (size_t)16 * lda;
  const u16* Bp = B + (size_t)(n0 + r) * ldb + kh * 8;

#pragma unroll 4
  for (int k0 = 0; k0 < K; k0 += 32) {
    bf16x8 a0 = *(const bf16x8*)(Ap0 + k0);
    bf16x8 a1 = *(const bf16x8*)(Ap1 + k0);
    bf16x8 bfr[NR];
#pragma unroll
    for (int ni = 0; ni < NR; ni++)
      bfr[ni] = *(const bf16x8*)(Bp + (size_t)ni * 16 * ldb + k0);
#pragma unroll
    for (int ni = 0; ni < NR; ni++) {
      acc[0][ni] = __builtin_amdgcn_mfma_f32_16x16x32_bf16(a0, bfr[ni], acc[0][ni], 0, 0, 0);
      acc[1][ni] = __builtin_amdgcn_mfma_f32_16x16x32_bf16(a1, bfr[ni], acc[1][ni], 0, 0, 0);
    }
  }

#pragma unroll
  for (int mi = 0; mi < 2; mi++) {
#pragma unroll
    for (int ni = 0; ni < NR; ni++) {
#pragma unroll
      for (int reg = 0; reg < 4; reg++) {
        int row = m0 + mi * 16 + kh * 4 + reg;
        int colx = n0 + ni * 16 + r;
        float v = acc[mi][ni][reg];
        if (bias) v += bias[colx];
        if (RELU) v = fmaxf(v, 0.f);
        if (Cf) Cf[(size_t)row * ldc + colx] = v;
        if (Cb) Cb[(size_t)row * ldc + colx] = to_bf16(v);
        if (VT) {
          if (colx >= 256) {
            int hv = (colx - 256) >> 5, dv = (colx - 256) & 31;
            vt[(size_t)hv * 32768 + (size_t)dv * 1024 + row] = to_bf16(v);
          }
        }
      }
    }
  }
}

// ---------------- per-wave flash-attention task ----------------------------
__device__ __forceinline__ void attn_task(
    int h, int q0, const u16* qkv, const u16* vt, u16* attnO, int lane)
{
  const int q = lane & 15, g = lane >> 4;
  const float iso = 0.17677669529663689f;

  bf16x8 qf = *(const bf16x8*)(qkv + (size_t)(q0 + q) * 384 + h * 32 + g * 8);
  const int kvo0 = 8 * (q >> 2) + (q & 3);
  const int kvo1 = kvo0 + 4;
  const u16* kbase = qkv + 128 + h * 32 + g * 8;
  const u16* vbase = vt + (size_t)h * 32768 + (size_t)q * 1024 + g * 8;

  f32x4 o0 = {0.f, 0.f, 0.f, 0.f}, o1 = {0.f, 0.f, 0.f, 0.f};
  float m = -1e30f, lsum = 0.f;
  const f32x4 zero = {0.f, 0.f, 0.f, 0.f};

  bf16x8 k0c = *(const bf16x8*)(kbase + (size_t)kvo0 * 384);
  bf16x8 k1c = *(const bf16x8*)(kbase + (size_t)kvo1 * 384);
  bf16x8 v0c = *(const bf16x8*)(vbase);
  bf16x8 v1c = *(const bf16x8*)(vbase + 16 * 1024);

  for (int kv0 = 0; kv0 < 1024; kv0 += 32) {
    const int nx = (kv0 + 32 < 1024) ? kv0 + 32 : kv0;
    bf16x8 k0n = *(const bf16x8*)(kbase + (size_t)(nx + kvo0) * 384);
    bf16x8 k1n = *(const bf16x8*)(kbase + (size_t)(nx + kvo1) * 384);
    bf16x8 v0n = *(const bf16x8*)(vbase + nx);
    bf16x8 v1n = *(const bf16x8*)(vbase + 16 * 1024 + nx);

    f32x4 s0 = __builtin_amdgcn_mfma_f32_16x16x32_bf16(k0c, qf, zero, 0, 0, 0);
    f32x4 s1 = __builtin_amdgcn_mfma_f32_16x16x32_bf16(k1c, qf, zero, 0, 0, 0);

    float tm = fmaxf(fmaxf(fmaxf(s0[0], s0[1]), fmaxf(s0[2], s0[3])),
                     fmaxf(fmaxf(s1[0], s1[1]), fmaxf(s1[2], s1[3])));
    tm = fmaxf(tm, __shfl_xor(tm, 16));
    tm = fmaxf(tm, __shfl_xor(tm, 32));
    float mn = fmaxf(m, tm);
    float corr = __expf((m - mn) * iso);

    float e0[4], e1v[4], sum = 0.f;
#pragma unroll
    for (int j = 0; j < 4; j++) {
      e0[j] = __expf((s0[j] - mn) * iso);
      e1v[j] = __expf((s1[j] - mn) * iso);
      sum += e0[j] + e1v[j];
    }
    lsum = lsum * corr + sum;
#pragma unroll
    for (int j = 0; j < 4; j++) { o0[j] *= corr; o1[j] *= corr; }

    union { u32 u[4]; bf16x8 v; } P;
    P.u[0] = packbf(e0[0], e0[1]);
    P.u[1] = packbf(e0[2], e0[3]);
    P.u[2] = packbf(e1v[0], e1v[1]);
    P.u[3] = packbf(e1v[2], e1v[3]);

    o0 = __builtin_amdgcn_mfma_f32_16x16x32_bf16(v0c, P.v, o0, 0, 0, 0);
    o1 = __builtin_amdgcn_mfma_f32_16x16x32_bf16(v1c, P.v, o1, 0, 0, 0);
    m = mn;
    k0c = k0n; k1c = k1n; v0c = v0n; v1c = v1n;
  }
  lsum += __shfl_xor(lsum, 16);
  lsum += __shfl_xor(lsum, 32);
  float inv = __builtin_amdgcn_rcpf(lsum);

  us4 w0, w1;
#pragma unroll
  for (int reg = 0; reg < 4; reg++) {
    w0[reg] = to_bf16(o0[reg] * inv);
    w1[reg] = to_bf16(o1[reg] * inv);
  }
  u16* outp = attnO + (size_t)(q0 + q) * 128 + h * 32 + 4 * g;
  *(us4*)outp = w0;
  *(us4*)(outp + 16) = w1;
}

// ---------------- per-block GEMM K=128 + bias + res + LN -------------------
__device__ __forceinline__ void owl_task(
    int m0, const u16* A, const u16* Bw, const float* bias, const float* Res,
    float* outF, u16* outB, const float* g_, const float* b_, char* smraw)
{
  float (*ld)[132] = (float(*)[132])smraw;
  const int tid = threadIdx.x;
  const int w = tid >> 6, l = tid & 63;
  const int r = l & 15, kg = l >> 4;

  f32x4 acc[2][2];
#pragma unroll
  for (int i = 0; i < 2; i++)
#pragma unroll
    for (int j = 0; j < 2; j++) acc[i][j] = (f32x4){0.f, 0.f, 0.f, 0.f};

  const u16* Ap0 = A + (size_t)(m0 + r) * 128 + kg * 8;
  const u16* Ap1 = Ap0 + (size_t)16 * 128;
  const u16* Bp0 = Bw + (size_t)(w * 32 + r) * 128 + kg * 8;
  const u16* Bp1 = Bp0 + (size_t)16 * 128;

#pragma unroll
  for (int k0 = 0; k0 < 128; k0 += 32) {
    bf16x8 a0 = *(const bf16x8*)(Ap0 + k0);
    bf16x8 a1 = *(const bf16x8*)(Ap1 + k0);
    bf16x8 b0 = *(const bf16x8*)(Bp0 + k0);
    bf16x8 b1 = *(const bf16x8*)(Bp1 + k0);
    acc[0][0] = __builtin_amdgcn_mfma_f32_16x16x32_bf16(a0, b0, acc[0][0], 0, 0, 0);
    acc[0][1] = __builtin_amdgcn_mfma_f32_16x16x32_bf16(a0, b1, acc[0][1], 0, 0, 0);
    acc[1][0] = __builtin_amdgcn_mfma_f32_16x16x32_bf16(a1, b0, acc[1][0], 0, 0, 0);
    acc[1][1] = __builtin_amdgcn_mfma_f32_16x16x32_bf16(a1, b1, acc[1][1], 0, 0, 0);
  }

#pragma unroll
  for (int mi = 0; mi < 2; mi++)
#pragma unroll
    for (int ni = 0; ni < 2; ni++)
#pragma unroll
      for (int reg = 0; reg < 4; reg++) {
        int row = mi * 16 + kg * 4 + reg;
        int col = w * 32 + ni * 16 + r;
        ld[row][col] = acc[mi][ni][reg] + bias[col] +
                       Res[(size_t)(m0 + row) * 128 + col];
      }
  __syncthreads();

  const int row = tid >> 3, s8 = tid & 7;
  f32x4 vv[4];
  float sum = 0.f, ss = 0.f;
#pragma unroll
  for (int u = 0; u < 4; u++) {
    vv[u] = *(const f32x4*)&ld[row][s8 * 16 + u * 4];
#pragma unroll
    for (int j = 0; j < 4; j++) { sum += vv[u][j]; ss += vv[u][j] * vv[u][j]; }
  }
#pragma unroll
  for (int off = 1; off <= 4; off <<= 1) {
    sum += __shfl_xor(sum, off);
    ss += __shfl_xor(ss, off);
  }
  float mu = sum * (1.f / 128.f);
  float var = ss * (1.f / 128.f) - mu * mu;
  float inv = rsqrtf(var + 1e-5f);
  size_t base = (size_t)(m0 + row) * 128;
#pragma unroll
  for (int u = 0; u < 4; u++) {
    int c = s8 * 16 + u * 4;
    f32x4 gv = *(const f32x4*)(g_ + c);
    f32x4 bv = *(const f32x4*)(b_ + c);
    f32x4 o;
    us4 ob;
#pragma unroll
    for (int j = 0; j < 4; j++) {
      o[j] = (vv[u][j] - mu) * inv * gv[j] + bv[j];
      ob[j] = to_bf16(o[j]);
    }
    *(f32x4*)(outF + base + c) = o;
    *(us4*)(outB + base + c) = ob;
  }
  __syncthreads();
}

// ---------------- per-wave residual + LN row task --------------------------
__device__ __forceinline__ void ln2r_task(
    int row, const float* pre, float* tS, u16* t_bf,
    const float* g_, const float* b_, int lane)
{
  size_t idx = (size_t)row * 128 + lane * 2;
  float2 pv = *(const float2*)(pre + idx);
  float2 rv = *(const float2*)(tS + idx);
  float vx = pv.x + rv.x, vy = pv.y + rv.y;
  float s = vx + vy;
#pragma unroll
  for (int off = 32; off >= 1; off >>= 1) s += __shfl_xor(s, off);
  float mu = s * (1.f / 128.f);
  float dx = vx - mu, dy = vy - mu;
  float q = dx * dx + dy * dy;
#pragma unroll
  for (int off = 32; off >= 1; off >>= 1) q += __shfl_xor(q, off);
  float inv = rsqrtf(q * (1.f / 128.f) + 1e-5f);
  float2 gv = *(const float2*)(g_ + lane * 2);
  float2 bv = *(const float2*)(b_ + lane * 2);
  float ox = dx * inv * gv.x + bv.x, oy = dy * inv * gv.y + bv.y;
  tS[idx] = ox; tS[idx + 1] = oy;
  t_bf[idx] = to_bf16(ox); t_bf[idx + 1] = to_bf16(oy);
}

// ---------------- persistent mega-kernel -----------------------------------
__global__ __launch_bounds__(256, 2) void mega_kernel(
    u16* wbf, float* wbias, float* z, u16* z_bf, float* tS, u16* t_bf,
    u16* qkv_bf, float* pre, float* R,
    const float* __restrict__ proj_w, const float* __restrict__ attn_in_w,
    const float* __restrict__ attn_out_w, const float* __restrict__ ff1_w,
    const float* __restrict__ ff2_w, const float* __restrict__ nh1_w,
    const float* __restrict__ e1_w, const float* __restrict__ e1_b,
    const float* __restrict__ p1_w, const float* __restrict__ p2_w,
    const float* __restrict__ proj_b, const float* __restrict__ attn_in_b,
    const float* __restrict__ attn_out_b,
    const float* __restrict__ ln1_g, const float* __restrict__ ln1_b,
    const float* __restrict__ ff1_b, const float* __restrict__ ff2_b,
    const float* __restrict__ ln2_g, const float* __restrict__ ln2_b,
    const float* __restrict__ nh1_b, const float* __restrict__ nh2_w,
    const float* __restrict__ nh2_b, const float* __restrict__ e2_w,
    const float* __restrict__ e2_b,
    const float* __restrict__ p1_b, const float* __restrict__ p2_b,
    float* out_node, float* out_edge, float* out_proj, unsigned* bar)
{
  __shared__ __align__(16) char smraw[49408];   // max(edge 49152, owl 16896)
  const int lane = threadIdx.x & 63;
  const int gw = blockIdx.x * 4 + (threadIdx.x >> 6);  // 0..2047
  const int gt = blockIdx.x * 256 + threadIdx.x;       // 0..131071

  u16*  pooled_bf = (u16*)R;
  u16*  attnO = (u16*)R;
  u16*  vt    = (u16*)R + 131072;
  u16*  fb    = (u16*)R;
  float* nhmid = R;
  float* e1out = R + 131072;
  u16*  pmid  = (u16*)(R + 393216);
  float* nullf = nullptr; u16* nullb = nullptr;

  // ---- stage 0: weights -> bf16 arena (+ e1 rearrange + wbias) ----
  for (int i = gt; i < 348160; i += 131072) {
    int i0 = i * 4;
    float v[4];
    if (i0 < 131072) {
      const float* s = proj_w + i0;
#pragma unroll
      for (int u = 0; u < 4; u++) v[u] = s[u];
    } else if (i0 < 229376) {
      const float* s = attn_in_w + (i0 - 131072);
#pragma unroll
      for (int u = 0; u < 4; u++) v[u] = s[u];
    } else if (i0 < 262144) {
      const float* s = attn_out_w + (i0 - 229376);
#pragma unroll
      for (int u = 0; u < 4; u++) v[u] = s[u];
    } else if (i0 < 786432) {
      const float* s = ff1_w + (i0 - 262144);
#pragma unroll
      for (int u = 0; u < 4; u++) v[u] = s[u];
    } else if (i0 < 1310720) {
      const float* s = ff2_w + (i0 - 786432);
#pragma unroll
      for (int u = 0; u < 4; u++) v[u] = s[u];
    } else if (i0 < 1327104) {
      const float* s = nh1_w + (i0 - 1310720);
#pragma unroll
      for (int u = 0; u < 4; u++) v[u] = s[u];
    } else if (i0 < 1359872) {
      int j = i0 - 1327104;
#pragma unroll
      for (int u = 0; u < 4; u++) {
        int idx = j + u, nn = idx >> 7, k = idx & 127;
        v[u] = e1_w[(nn & 127) * 256 + (nn >> 7) * 128 + k];
      }
    } else if (i0 < 1376256) {
      const float* s = p1_w + (i0 - 1359872);
#pragma unroll
      for (int u = 0; u < 4; u++) v[u] = s[u];
    } else {
      const float* s = p2_w + (i0 - 1376256);
#pragma unroll
      for (int u = 0; u < 4; u++) v[u] = s[u];
    }
    us4 o;
#pragma unroll
    for (int u = 0; u < 4; u++) o[u] = to_bf16(v[u]);
    *(us4*)(wbf + i0) = o;
  }
  if (gt < 256) wbias[gt] = (gt < 128) ? 0.f : e1_b[gt - 128];
  gsync(bar, 0);

  // ---- stage 1: z = pooled @ proj_w^T + proj_b ----
  if (gw < 128)
    mm_task<2, 1024, false, false>((gw >> 2) * 32, (gw & 3) * 32,
        pooled_bf, 1024, wbf, 1024, proj_b, z, z_bf, nullb, 128, lane);
  gsync(bar, 1);

  int bi = 2;
  for (int l = 0; l < 2; l++) {
    const float* resIn = l ? tS : z;
    const u16* tin_bf = l ? t_bf : z_bf;
    if (gw < 192)
      mm_task<4, 128, false, true>((gw / 6) * 32, (gw % 6) * 64,
          tin_bf, 128, wbf + 131072 + l * 49152, 128, attn_in_b + l * 384,
          nullf, qkv_bf, vt, 384, lane);
    gsync(bar, bi++);
    if (gw < 256) attn_task(gw >> 6, (gw & 63) * 16, qkv_bf, vt, attnO, lane);
    gsync(bar, bi++);
    if (blockIdx.x < 32)
      owl_task(blockIdx.x * 32, attnO, wbf + 229376 + l * 16384,
               attn_out_b + l * 128, resIn, tS, t_bf,
               ln1_g + l * 128, ln1_b + l * 128, smraw);
    gsync(bar, bi++);
    if (gw < 1024)
      mm_task<4, 128, true, false>((gw >> 5) * 32, (gw & 31) * 64,
          t_bf, 128, wbf + 262144 + l * 262144, 128, ff1_b + l * 2048,
          nullf, fb, nullb, 2048, lane);
    gsync(bar, bi++);
    if (gw < 64)
      mm_task<4, 2048, false, false>((gw >> 1) * 32, (gw & 1) * 64,
          fb, 2048, wbf + 786432 + l * 262144, 2048, ff2_b + l * 128,
          pre, nullb, nullb, 128, lane);
    gsync(bar, bi++);
    if (gw < 1024)
      ln2r_task(gw, pre, tS, t_bf, ln2_g + l * 128, ln2_b + l * 128, lane);
    gsync(bar, bi++);
  }

  // ---- stage headA: nh1 | e1 (combined hi|hj) | p1 ----
  if (gw < 128) {
    mm_task<2, 128, true, false>((gw >> 2) * 32, (gw & 3) * 32,
        t_bf, 128, wbf + 1310720, 128, nh1_b, nhmid, nullb, nullb, 128, lane);
  } else if (gw < 384) {
    int t = gw - 128;
    mm_task<2, 128, false, false>((t >> 3) * 32, (t & 7) * 32,
        t_bf, 128, wbf + 1327104, 128, wbias, e1out, nullb, nullb, 256, lane);
  } else if (gw < 512) {
    int t = gw - 384;
    mm_task<2, 128, true, false>((t >> 2) * 32, (t & 3) * 32,
        z_bf, 128, wbf + 1359872, 128, p1_b, nullf, pmid, nullb, 128, lane);
  }
  gsync(bar, 14);

  // ---- stage headB: edge (all 512 blocks) + nh2 + p2 ----
  {
    float (*his)[64] = (float(*)[64])smraw;
    float (*hjs)[32] = (float(*)[32])(smraw + 32768);
    const int i0 = (blockIdx.x & 15) * 64;
    const int j0 = (blockIdx.x >> 4) * 32;
    const int tid = threadIdx.x;
    {
      int r = tid >> 2, c0 = (tid & 3) * 32;
#pragma unroll
      for (int u = 0; u < 8; u++) {
        float4 v = *(const float4*)(e1out + (size_t)(i0 + r) * 256 + c0 + u * 4);
        his[c0 + u * 4 + 0][r] = v.x; his[c0 + u * 4 + 1][r] = v.y;
        his[c0 + u * 4 + 2][r] = v.z; his[c0 + u * 4 + 3][r] = v.w;
      }
    }
    {
      int r = tid >> 3, c0 = (tid & 7) * 16;
#pragma unroll
      for (int u = 0; u < 4; u++) {
        float4 v = *(const float4*)(e1out + (size_t)(j0 + r) * 256 + 128 + c0 + u * 4);
        hjs[c0 + u * 4 + 0][r] = v.x; hjs[c0 + u * 4 + 1][r] = v.y;
        hjs[c0 + u * 4 + 2][r] = v.z; hjs[c0 + u * 4 + 3][r] = v.w;
      }
    }
    __syncthreads();
    const int il = (tid & 15) * 4, jl = (tid >> 4) * 2;
    float acc[4][2] = {{0.f,0.f},{0.f,0.f},{0.f,0.f},{0.f,0.f}};
    for (int e = 0; e < 128; e++) {
      float4 a = *(const float4*)&his[e][il];
      float2 bv = *(const float2*)&hjs[e][jl];
      float we = e2_w[e];
      float av[4] = {a.x, a.y, a.z, a.w};
      float bb[2] = {bv.x, bv.y};
#pragma unroll
      for (int ii = 0; ii < 4; ii++)
#pragma unroll
        for (int jj = 0; jj < 2; jj++)
          acc[ii][jj] += fmaxf(av[ii] + bb[jj], 0.f) * we;
    }
    float eb = e2_b[0];
#pragma unroll
    for (int ii = 0; ii < 4; ii++) {
      float2 vv = make_float2(acc[ii][0] + eb, acc[ii][1] + eb);
      *(float2*)(out_edge + (size_t)(i0 + il + ii) * 1024 + j0 + jl) = vv;
    }
  }
  // nh2: one thread per row (global threads 0..1023)
  if (gt < 1024) {
    const float* row = nhmid + (size_t)gt * 128;
    float a0 = 0.f, a1 = 0.f, a2 = 0.f;
#pragma unroll 8
    for (int k = 0; k < 128; k += 4) {
      float4 v = *(const float4*)(row + k);
      a0 += v.x * nh2_w[k] + v.y * nh2_w[k + 1] + v.z * nh2_w[k + 2] + v.w * nh2_w[k + 3];
      a1 += v.x * nh2_w[128 + k] + v.y * nh2_w[128 + k + 1] + v.z * nh2_w[128 + k + 2] + v.w * nh2_w[128 + k + 3];
      a2 += v.x * nh2_w[256 + k] + v.y * nh2_w[256 + k + 1] + v.z * nh2_w[256 + k + 2] + v.w * nh2_w[256 + k + 3];
    }
    out_node[gt * 3 + 0] = a0 + nh2_b[0];
    out_node[gt * 3 + 1] = a1 + nh2_b[1];
    out_node[gt * 3 + 2] = a2 + nh2_b[2];
  }
  // p2: waves 1920..2047
  if (gw >= 1920) {
    int t = gw - 1920;
    mm_task<2, 128, false, false>((t >> 2) * 32, (t & 3) * 32,
        pmid, 128, wbf + 1376256, 128, p2_b, out_proj, nullb, nullb, 128, lane);
  }
}

// ---------------------------------------------------------------------------
extern "C" void kernel_launch(void* const* d_in, const int* in_sizes, int n_in,
                              void* d_out, int out_size, void* d_ws, size_t ws_size,
                              hipStream_t stream)
{
  const float* x        = (const float*)d_in[0];
  const float* conv1_w  = (const float*)d_in[1];
  const float* conv1_b  = (const float*)d_in[2];
  const float* bn1_g    = (const float*)d_in[3];
  const float* bn1_b    = (const float*)d_in[4];
  const float* bn1_m    = (const float*)d_in[5];
  const float* bn1_v    = (const float*)d_in[6];
  const float* conv2_w  = (const float*)d_in[7];
  const float* conv2_b  = (const float*)d_in[8];
  const float* bn2_g    = (const float*)d_in[9];
  const float* bn2_b    = (const float*)d_in[10];
  const float* bn2_m    = (const float*)d_in[11];
  const float* bn2_v    = (const float*)d_in[12];
  const float* proj_w   = (const float*)d_in[13];
  const float* proj_b   = (const float*)d_in[14];
  const float* attn_in_w  = (const float*)d_in[15];
  const float* attn_in_b  = (const float*)d_in[16];
  const float* attn_out_w = (const float*)d_in[17];
  const float* attn_out_b = (const float*)d_in[18];
  const float* ln1_g    = (const float*)d_in[19];
  const float* ln1_b    = (const float*)d_in[20];
  const float* ff1_w    = (const float*)d_in[21];
  const float* ff1_b    = (const float*)d_in[22];
  const float* ff2_w    = (const float*)d_in[23];
  const float* ff2_b    = (const float*)d_in[24];
  const float* ln2_g    = (const float*)d_in[25];
  const float* ln2_b    = (const float*)d_in[26];
  const float* nh1_w    = (const float*)d_in[27];
  const float* nh1_b    = (const float*)d_in[28];
  const float* nh2_w    = (const float*)d_in[29];
  const float* nh2_b    = (const float*)d_in[30];
  const float* e1_w     = (const float*)d_in[31];
  const float* e1_b     = (const float*)d_in[32];
  const float* e2_w     = (const float*)d_in[33];
  const float* e2_b     = (const float*)d_in[34];
  const float* p1_w     = (const float*)d_in[35];
  const float* p1_b     = (const float*)d_in[36];
  const float* p2_w     = (const float*)d_in[37];
  const float* p2_b     = (const float*)d_in[38];

  float* ws = (float*)d_ws;

  // bar[16] at ws[0..16); arena shifted +16 f32. Total 2,466,064 f32 = 9.41 MiB.
  unsigned* bar = (unsigned*)ws;
  float* base  = ws + 16;
  u16*  wbf    = (u16*)base;                     // 1392640 u16
  float* wbias = base + 696320;                  // 256 f32
  float* z     = base + 696576;                  // 131072
  u16*  z_bf   = (u16*)(base + 827648);          // 131072 u16
  float* tS    = base + 893184;                  // 131072
  u16*  t_bf   = (u16*)(base + 1024256);         // 131072 u16
  u16*  qkv_bf = (u16*)(base + 1089792);         // 393216 u16
  float* pre   = base + 1286400;                 // 131072 f32
  float* R     = base + 1417472;                 // 1048576 f32 shared region
  u16*  pooled_bf = (u16*)R;

  float* out_node = (float*)d_out;
  float* out_edge = out_node + 3072;
  float* out_proj = out_edge + 1048576;

  hipMemsetAsync(bar, 0, 64, stream);

  encoder_kernel<<<2048, 256, 0, stream>>>(
      x, conv1_w, conv1_b, bn1_g, bn1_b, bn1_m, bn1_v,
      conv2_w, conv2_b, bn2_g, bn2_b, bn2_m, bn2_v, pooled_bf);

  mega_kernel<<<512, 256, 0, stream>>>(
      wbf, wbias, z, z_bf, tS, t_bf, qkv_bf, pre, R,
      proj_w, attn_in_w, attn_out_w, ff1_w, ff2_w, nh1_w, e1_w, e1_b,
      p1_w, p2_w,
      proj_b, attn_in_b, attn_out_b, ln1_g, ln1_b, ff1_b, ff2_b,
      ln2_g, ln2_b, nh1_b, nh2_w, nh2_b, e2_w, e2_b, p1_b, p2_b,
      out_node, out_edge, out_proj, bar);
}